// Round 1
// 102.622 us; speedup vs baseline: 1.0031x; 1.0031x over previous
//
#include <hip/hip_runtime.h>

// Mo3ENet neighbor selection: B=256, PER=1024, NIN=256, NOUT=768, K=32, R=6
// Round 9: 16 targets/block (4 per wave, sequential), grid 16384->4096 to
// amortize the 12 KB batch staging 4x; SALU self-exclusion (ballot-mask
// clear) instead of per-lane !=i compare; v_cndmask directly off the ballot
// SGPR pair for slot/dump selection.
// Outputs (concatenated float32):
//   [0) src_ii | [E) tgt | [2E) m_ii | [3E) dist_ii |
//   [4E) src_io | [5E) tgt | [6E) m_io | [7E) dist_io
//
// Per-wave LDS slot row (128 ints): [0..31] ii slots | [32..63] io slots |
// [64..127] dead (dump + spill). ii main/pad may spill into 32..63 — always
// overwritten later by io main+pad (program order within the same wave).
// Row is reused across the wave's 4 targets (epilogue of target t reads it
// before target t+1 rewrites it — same-wave program order, no barrier).

constexpr int KK = 32;
constexpr unsigned EE = 2097152u;  // elements per output array

typedef float v2f __attribute__((ext_vector_type(2)));

__device__ __forceinline__ v2f pk_add(v2f a, v2f b) {
    v2f d; asm("v_pk_add_f32 %0, %1, %2" : "=v"(d) : "v"(a), "v"(b)); return d;
}
__device__ __forceinline__ v2f pk_mul(v2f a, v2f b) {
    v2f d; asm("v_pk_mul_f32 %0, %1, %2" : "=v"(d) : "v"(a), "v"(b)); return d;
}

__device__ __forceinline__ int prefix_lt(unsigned long long m) {
    return __builtin_amdgcn_mbcnt_hi((unsigned)(m >> 32),
           __builtin_amdgcn_mbcnt_lo((unsigned)m, 0u));
}

// d = bit_l(m) ? b : a  — v_cndmask off an arbitrary SGPR-pair mask.
__device__ __forceinline__ int sel_mask(int a, int b, unsigned long long m) {
    int d; asm("v_cndmask_b32 %0, %1, %2, %3" : "=v"(d) : "v"(a), "v"(b), "s"(m));
    return d;
}

__global__ __launch_bounds__(256) void mo3e_kernel(const float* __restrict__ pos,
                                                   float* __restrict__ out) {
    __shared__ float sq[3072];          // flat xyz, 12 KB
    __shared__ int   slotrow[4][128];   // 2 KB, one row per wave

    const int blk = blockIdx.x;
    const int b   = blk >> 4;           // 16 blocks per batch
    const int tid = threadIdx.x;
    const int w   = tid >> 6;
    const int l   = tid & 63;
    const int ibase = ((blk & 15) << 4) | (w << 2);   // 4 targets per wave

    // Stage batch positions: 3 coalesced float4 per thread.
    {
        const float4* g4 = (const float4*)(pos + (size_t)b * 3072);
        float4* s4 = (float4*)sq;
        s4[tid      ] = g4[tid      ];
        s4[tid + 256] = g4[tid + 256];
        s4[tid + 512] = g4[tid + 512];
    }
    __syncthreads();

    int* __restrict__ row = slotrow[w];
    const int dump = 64 + l;            // per-lane dead entry (conflict-free)

    for (int t = 0; t < 4; ++t) {
        const int i = __builtin_amdgcn_readfirstlane(ibase + t);

        const float xi = sq[3 * i], yi = sq[3 * i + 1], zi = sq[3 * i + 2];
        // (q + (-t)) == (q - t); (q-t)^2 == (t-q)^2 bitwise. Per-half op order
        // (dx^2 + dy^2) + dz^2 matches the reference exactly; asm pk ops cannot
        // be contracted. Predicate d2 < 36.0f is bit-identical to sqrt(d2) < 6.
        const v2f nx = {-xi, -xi}, ny = {-yi, -yi}, nz = {-zi, -zi};

        // Self-exclusion moved to SALU: clear bit (i&63) of the one ii group
        // containing i (self d2=0 always passes the distance test).
        const int gself = i >> 6;                       // 0..3
        const unsigned long long selfclr = ~(1ull << (i & 63));

        unsigned long long msk[16];
        int cii = 0, cio = 0;
        int av = 3 * l;                 // dword index of cand (c0 + l) x-coord

        // ============ ii scan: iters 0..1, candidates [0,256) ============
#pragma unroll
        for (int it = 0; it < 2; ++it) {
            const float xa = sq[av], ya = sq[av + 1], za = sq[av + 2];
            const float xb = sq[av + 192], yb = sq[av + 193], zb = sq[av + 194];
            av += 384;
            const v2f qx = {xa, xb}, qy = {ya, yb}, qz = {za, zb};
            const v2f dx = pk_add(qx, nx), dy = pk_add(qy, ny), dz = pk_add(qz, nz);
            const v2f d2 = pk_add(pk_add(pk_mul(dx, dx), pk_mul(dy, dy)), pk_mul(dz, dz));
            const int c0 = it * 128;
            {   // group 2*it: candidates [c0, c0+64)
                unsigned long long m = __ballot(d2.x < 36.0f);
                if (2 * it == gself) m &= selfclr;      // wave-uniform SALU
                msk[2 * it] = m;
                int ent = cii + prefix_lt(m);
                ent = ent < 127 ? ent : 127;            // spill -> dead/overwritten
                row[sel_mask(dump, ent, m)] = c0 + l;
                cii += __popcll(m);
            }
            {   // group 2*it+1: candidates [c0+64, c0+128)
                unsigned long long m = __ballot(d2.y < 36.0f);
                if (2 * it + 1 == gself) m &= selfclr;
                msk[2 * it + 1] = m;
                int ent = cii + prefix_lt(m);
                ent = ent < 127 ? ent : 127;
                row[sel_mask(dump, ent, m)] = c0 + 64 + l;
                cii += __popcll(m);
            }
        }
        const int S0ii = cii < KK ? cii : KK;
        if (cii < KK) {  // ii pad: smallest invalid indices (incl. j==i)
            int pc = cii;
#pragma unroll
            for (int g = 0; g < 4; ++g) {
                const unsigned long long inv = ~msk[g];
                int ent = pc + prefix_lt(inv);          // max 31+63=94: dead/overwritten
                row[sel_mask(dump, ent, inv)] = g * 64 + l;
                pc += __popcll(inv);
                if (pc >= KK) break;                    // inv dense: ~1 iteration
            }
        }

        // ============ io scan: iters 2..7, candidates [256,1024) ============
#pragma unroll
        for (int it = 2; it < 8; ++it) {
            const float xa = sq[av], ya = sq[av + 1], za = sq[av + 2];
            const float xb = sq[av + 192], yb = sq[av + 193], zb = sq[av + 194];
            av += 384;
            const v2f qx = {xa, xb}, qy = {ya, yb}, qz = {za, zb};
            const v2f dx = pk_add(qx, nx), dy = pk_add(qy, ny), dz = pk_add(qz, nz);
            const v2f d2 = pk_add(pk_add(pk_mul(dx, dx), pk_mul(dy, dy)), pk_mul(dz, dz));
            const int c0 = it * 128;
            {
                const unsigned long long m = __ballot(d2.x < 36.0f);
                msk[2 * it] = m;
                int ent = cio + prefix_lt(m);
                ent = ent < 95 ? ent : 95;              // +32 => max 127 (dead)
                row[sel_mask(dump, ent + KK, m)] = c0 + l;
                cio += __popcll(m);
            }
            {
                const unsigned long long m = __ballot(d2.y < 36.0f);
                msk[2 * it + 1] = m;
                int ent = cio + prefix_lt(m);
                ent = ent < 95 ? ent : 95;
                row[sel_mask(dump, ent + KK, m)] = c0 + 64 + l;
                cio += __popcll(m);
            }
        }
        const int S0io = cio < KK ? cio : KK;
        if (cio < KK) {  // io pad
            int pc = cio;
#pragma unroll
            for (int g = 4; g < 16; ++g) {
                const unsigned long long inv = ~msk[g];
                int ent = pc + prefix_lt(inv);          // +32 => max 126 (dead)
                row[sel_mask(dump, ent + KK, inv)] = g * 64 + l;
                pc += __popcll(inv);
                if (pc >= KK) break;
            }
        }

        // ===== epilogue: lane l reads entry l (0..31 ii, 32..63 io), 4 coalesced stores =====
        {
            const int idx = row[l];                     // same-wave RAW: no barrier needed
            const float qx = sq[3 * idx], qy = sq[3 * idx + 1], qz = sq[3 * idx + 2];
            const float ddx = xi - qx, ddy = yi - qy, ddz = zi - qz;
            const float d2e = ddx * ddx + ddy * ddy + ddz * ddz;  // dist tol ~0.03: any order

            const bool isA = l < KK;
            const int  S0  = isA ? S0ii : S0io;
            const bool mv  = (l & 31) < S0;
            const float dist = mv ? __builtin_amdgcn_sqrtf(d2e) : 0.0f;

            const int goff = b * 1024;
            const unsigned e0  = (unsigned)(b * 256 + i) * 32u;
            const unsigned off = (isA ? 0u : 4u * EE - 32u) + e0 + (unsigned)l;

            out[off]           = (float)(goff + idx);   // src (io idx already >= 256)
            out[off + EE]      = (float)(goff + i);     // tgt
            out[off + 2u * EE] = mv ? 1.0f : 0.0f;      // mask
            out[off + 3u * EE] = dist;                  // dist
        }
    }
}

extern "C" void kernel_launch(void* const* d_in, const int* in_sizes, int n_in,
                              void* d_out, int out_size, void* d_ws, size_t ws_size,
                              hipStream_t stream) {
    const float* pos = (const float*)d_in[0];
    float* out = (float*)d_out;

    // 16 blocks/batch x 256 batches; 256 threads = 4 waves = 16 targets/block.
    mo3e_kernel<<<dim3(256 * 16), dim3(256), 0, stream>>>(pos, out);
}